// Round 19
// baseline (255.831 us; speedup 1.0000x reference)
//
#include <hip/hip_runtime.h>
#include <math.h>

#define NSITE 100
#define NOCC  50
#define DIM   128
#define KDET  4
#define NTAB  400                         // K*(N_UP+N_DOWN)
#define TP_FLOATS ((4 + 144) * NTAB)      // T then P' in ws

// ---------------------------------------------------------------------------
// R18 ALGORITHMIC COLLAPSE: phi[r][j] = tok[c]·W_j + pos[s]·W_j + b_j with
// batch-independent tok/pos/W -> precompute T[4][400], P'[144][400] once;
// the per-batch GEMM becomes 2 loads + 1 add per element (197us det @ 89%
// VALUBusy). Remaining bloat = spill from load-transient peak: 12-column
// load groups held 24 float2 regs in flight -> peak ~80 > budget 73 at (7).
// R19: waves_per_eu(6) (budget 85) + 8-column load groups (16 in flight)
// -> peak ~72, margin 13 -- the RA's measured-safe regime.
// ---------------------------------------------------------------------------

// Wave64 max-reduction via DPP (VALU-only). Lane 63 ends with global max.
__device__ __forceinline__ unsigned dpp_max64_to_lane63(unsigned x) {
  unsigned t;
  t = (unsigned)__builtin_amdgcn_update_dpp((int)x, (int)x, 0x111, 0xf, 0xf, false);
  x = x > t ? x : t;
  t = (unsigned)__builtin_amdgcn_update_dpp((int)x, (int)x, 0x112, 0xf, 0xf, false);
  x = x > t ? x : t;
  t = (unsigned)__builtin_amdgcn_update_dpp((int)x, (int)x, 0x114, 0xf, 0xf, false);
  x = x > t ? x : t;
  t = (unsigned)__builtin_amdgcn_update_dpp((int)x, (int)x, 0x118, 0xf, 0xf, false);
  x = x > t ? x : t;
  t = (unsigned)__builtin_amdgcn_update_dpp((int)x, (int)x, 0x142, 0xa, 0xf, false);
  x = x > t ? x : t;
  t = (unsigned)__builtin_amdgcn_update_dpp((int)x, (int)x, 0x143, 0xc, 0xf, false);
  x = x > t ? x : t;
  return x;
}

#define REPA(X) X(0) X(1) X(2) X(3) X(4) X(5) X(6) X(7) X(8) X(9) \
  X(10) X(11) X(12) X(13) X(14) X(15) X(16) X(17) X(18) X(19) \
  X(20) X(21) X(22) X(23) X(24) X(25) X(26) X(27) X(28) X(29) \
  X(30) X(31) X(32) X(33) X(34) X(35) X(36) X(37) X(38) X(39) \
  X(40) X(41) X(42) X(43) X(44) X(45) X(46) X(47) X(48) X(49)
#define REPB(X) X(0) X(1) X(2) X(3) X(4) X(5) X(6) X(7) X(8) X(9) \
  X(10) X(11) X(12) X(13) X(14) X(15) X(16) X(17) X(18) X(19) \
  X(20) X(21) X(22) X(23) X(24) X(25) X(26) X(27) X(28) X(29) \
  X(30) X(31) X(32) X(33) X(34) X(35) X(36) X(37) X(38) X(39) \
  X(40) X(41) X(42) X(43) X(44) X(45) X(46) X(47) X(48) X(49)

// ---- Precompute: T[c][j] = tok[c].W_j ; P'[s][j] = pos[s].W_j + b_j ------
__global__ __launch_bounds__(256) void tp_kernel(
    const float* __restrict__ tok, const float* __restrict__ pos,
    const float* __restrict__ W,   const float* __restrict__ bvec,
    float* __restrict__ T, float* __restrict__ P)
{
  const int gid = blockIdx.x * 256 + threadIdx.x;
  if (gid >= 148 * NTAB) return;
  const int row = gid / NTAB;
  const int col = gid - row * NTAB;
  const float4* h4 = (const float4*)((row < 4) ? (tok + (size_t)row * DIM)
                                               : (pos + (size_t)(row - 4) * DIM));
  const float4* w4 = (const float4*)(W + (size_t)col * DIM);
  float acc = 0.0f;
  #pragma unroll
  for (int i = 0; i < DIM / 4; ++i) {
    float4 a = h4[i], b = w4[i];
    acc = fmaf(a.x, b.x, acc);
    acc = fmaf(a.y, b.y, acc);
    acc = fmaf(a.z, b.z, acc);
    acc = fmaf(a.w, b.w, acc);
  }
  if (row < 4) T[(size_t)row * NTAB + col] = acc;
  else         P[(size_t)(row - 4) * NTAB + col] = acc + bvec[col];
}

// One block per (batch, spin). Wave w handles determinant k=w.
// Lane r owns row r of phi in 50 named fp32 registers (r < 50).
__global__ __launch_bounds__(256)
__attribute__((amdgpu_waves_per_eu(6)))
void det_kernel(
    const int*   __restrict__ configs,   // (B,100) int32
    const float* __restrict__ T,         // (4,400)
    const float* __restrict__ P,         // (144,400)  includes bias
    double*      __restrict__ dets)      // (B,2,4,2)  {logdet, sign}
{
  const int b    = blockIdx.x;
  const int spin = blockIdx.y;

  __shared__ int cfg[NSITE];
  __shared__ int idx[NOCC];
  __shared__ int occl[NOCC];
  __shared__ int filll[NOCC];
  __shared__ int perm[4][NOCC];

  const int tid = threadIdx.x;
  if (tid < NSITE) cfg[tid] = configs[(size_t)b * NSITE + tid];
  __syncthreads();

  // Occupied-index list per reference argsort semantics: all occupied sites
  // (ascending, capped 50) + smallest unoccupied fill, merged sorted.
  if (tid == 0) {
    int no = 0, nf = 0;
    for (int n = 0; n < NSITE; ++n) {
      int c = cfg[n];
      bool occ = (spin == 0) ? (c == 1 || c == 3) : (c == 2 || c == 3);
      if (occ) { if (no < NOCC) occl[no++]  = n; }
      else     { if (nf < NOCC) filll[nf++] = n; }
    }
    int need = NOCC - no; if (need < 0) need = 0;
    int i = 0, j = 0;
    for (int k = 0; k < NOCC; ++k) {
      bool takeocc = (i < no) && (j >= need || occl[i] < filll[j]);
      idx[k] = takeocc ? occl[i++] : filll[j++];
    }
  }
  __syncthreads();

  const int lane = tid & 63;
  const int wave = tid >> 6;
  const int wave_u  = __builtin_amdgcn_readfirstlane(wave);
  const int colbase = spin * 200 + wave_u * 50;          // uniform

  const bool act  = (lane < NOCC);
  const int  site = idx[act ? lane : 0];
  const int  cc0  = cfg[site];
  // colbase is a multiple of 50 (even) -> float2-aligned offsets.
  const float2* T2 = (const float2*)(T + (size_t)cc0  * NTAB + colbase);
  const float2* P2 = (const float2*)(P + (size_t)site * NTAB + colbase);

  // ---- assemble phi row: q_j = T[c][cb+j] + P'[site][cb+j] ----
  #define DECLQ(i) float q##i;
  REPB(DECLQ)
  #undef DECLQ
  // 4 LQ (8 columns, 16 float regs in flight) per sched_barrier: bounds the
  // load-transient peak to ~72 total < 85 budget (R18's 12-col groups hit
  // ~80 > 73 -> spill).
  #define LQ(i0, i1) { float2 a = T2[(i0) / 2], c = P2[(i0) / 2]; \
      q##i0 = a.x + c.x; q##i1 = a.y + c.y; }
  LQ(0, 1)  LQ(2, 3)  LQ(4, 5)  LQ(6, 7)
  __builtin_amdgcn_sched_barrier(0);
  LQ(8, 9)  LQ(10, 11) LQ(12, 13) LQ(14, 15)
  __builtin_amdgcn_sched_barrier(0);
  LQ(16, 17) LQ(18, 19) LQ(20, 21) LQ(22, 23)
  __builtin_amdgcn_sched_barrier(0);
  LQ(24, 25) LQ(26, 27) LQ(28, 29) LQ(30, 31)
  __builtin_amdgcn_sched_barrier(0);
  LQ(32, 33) LQ(34, 35) LQ(36, 37) LQ(38, 39)
  __builtin_amdgcn_sched_barrier(0);
  LQ(40, 41) LQ(42, 43) LQ(44, 45) LQ(46, 47)
  __builtin_amdgcn_sched_barrier(0);
  LQ(48, 49)
  #undef LQ

  // zero inactive lanes so they never win the pivot and updates stay benign
  #define ZEROQ(i) q##i = act ? q##i : 0.0f;
  REPB(ZEROQ)
  #undef ZEROQ

  // ---- LU (fp32, in place on q) with implicit partial pivoting ----------
  float  mant_prod = 1.0f;     // product of pivot mantissas in [1,2): < 2^50
  int    esum = 0, neg = 0, mystep = -1;
  unsigned alive = act ? 1u : 0u;

  #define UPD(CC) if ((CC) > cJ) { \
      const float pc = __int_as_float( \
          __builtin_amdgcn_readlane(__float_as_int(q##CC), p)); \
      q##CC = fmaf(-mult, pc, q##CC); }
  #define LUS(J) { \
    const unsigned ab = __float_as_uint(q##J) & 0x7FFFFFFFu; \
    unsigned key = alive ? ((ab & ~63u) | (unsigned)lane) : 0u; \
    key = dpp_max64_to_lane63(key); \
    const int p = __builtin_amdgcn_readlane((int)key, 63) & 63; \
    const float piv = __int_as_float( \
        __builtin_amdgcn_readlane(__float_as_int(q##J), p)); \
    const unsigned pb = __float_as_uint(piv); \
    esum += (int)((pb >> 23) & 0xFFu) - 127; \
    neg  += (int)(pb >> 31); \
    mant_prod *= __uint_as_float((pb & 0x007FFFFFu) | 0x3F800000u); \
    if (lane == p) mystep = (J); \
    alive &= (lane != p) ? 1u : 0u; \
    const float rp = (piv != 0.0f) ? 1.0f / piv : 0.0f; \
    const float mult = alive ? q##J * rp : 0.0f; \
    const int cJ = (J); \
    REPB(UPD) \
  }
  REPA(LUS)
  #undef LUS
  #undef UPD

  const double logdet =
      log((double)mant_prod) + (double)esum * 0.6931471805599453;

  // permutation parity: perm[step] = lane chosen at that step (LDS)
  if (mystep >= 0) perm[wave][mystep] = lane;
  __syncthreads();
  int pj  = perm[wave][act ? lane : 0];
  int inv = 0;
  for (int i = 0; i < NOCC; ++i) {
    int pi = perm[wave][i];
    inv += (act && i < lane && pi > pj) ? 1 : 0;
  }
  #pragma unroll
  for (int m = 32; m >= 1; m >>= 1) inv += __shfl_xor(inv, m, 64);

  const int sgn = ((neg + inv) & 1) ? -1 : 1;
  if (lane == 0) {
    size_t o = (((size_t)b * 2 + spin) * KDET + wave) * 2;
    dets[o]     = logdet;
    dets[o + 1] = (double)sgn;
  }
}

// PLANAR complex64 output: out[0..B) = log_abs (real), out[B..2B) = phase (imag)
__global__ __launch_bounds__(256) void combine_kernel(
    const double* __restrict__ dets, float* __restrict__ out, int B)
{
  int b = blockIdx.x * blockDim.x + threadIdx.x;
  if (b >= B) return;
  const double* du = dets + ((size_t)b * 2 + 0) * KDET * 2;
  const double* dd = dets + ((size_t)b * 2 + 1) * KDET * 2;
  double t[KDET], s[KDET], m = -1e300;
  #pragma unroll
  for (int k = 0; k < KDET; ++k) {
    t[k] = du[2 * k] + dd[2 * k];
    s[k] = du[2 * k + 1] * dd[2 * k + 1];
    if (t[k] > m) m = t[k];
  }
  double sum = 0.0;
  #pragma unroll
  for (int k = 0; k < KDET; ++k) {
    if (t[k] > -1e290) sum += s[k] * exp(t[k] - m);
  }
  double p  = (m > -1e290) ? exp(m) * fabs(sum) : 0.0;
  double la = log(p + 1e-30);                    // reproduce ref clamp exactly
  float phase = (sum >= 0.0) ? 0.0f : 3.14159265358979f;
  out[b]     = (float)la;
  out[B + b] = phase;
}

extern "C" void kernel_launch(void* const* d_in, const int* in_sizes, int n_in,
                              void* d_out, int out_size, void* d_ws, size_t ws_size,
                              hipStream_t stream) {
  const int*   configs = (const int*)  d_in[0];
  const float* tok     = (const float*)d_in[1];
  const float* pos     = (const float*)d_in[2];
  const float* W       = (const float*)d_in[3];
  const float* bv      = (const float*)d_in[4];

  float*  wsf  = (float*)d_ws;
  float*  T    = wsf;                       // 4*400 floats
  float*  P    = wsf + 4 * NTAB;            // 144*400 floats
  double* dets = (double*)(wsf + TP_FLOATS);  // 236800B offset, 8-aligned
  const int B = in_sizes[0] / NSITE;        // total ws: ~499KB

  tp_kernel<<<(148 * NTAB + 255) / 256, 256, 0, stream>>>(tok, pos, W, bv, T, P);
  dim3 grid(B, 2);
  det_kernel<<<grid, 256, 0, stream>>>(configs, T, P, dets);
  combine_kernel<<<(B + 255) / 256, 256, 0, stream>>>(dets, (float*)d_out, B);
}